// Round 17
// baseline (112.581 us; speedup 1.0000x reference)
//
#include <hip/hip_runtime.h>
#include <hip/hip_bf16.h>

// Problem constants
#define BB 4
#define CC 128
#define NN 4096
#define KK 32
// ws layout (floats)
#define THETA_OFF  0
#define THETA_SZ   (BB*NN*CC)            // 2097152 floats (8 MB)
#define M_OFF      (THETA_OFF + THETA_SZ)
#define M_SZ       (CC*CC)
#define B2_OFF     (M_OFF + M_SZ)
#define PART_OFF   (B2_OFF + 128)
#define PART_SZ    (1024*256)
#define PART2_OFF  (PART_OFF + PART_SZ)
#define PART2_SZ   (64*256)

__device__ __forceinline__ float dot4(float4 a, float4 b) {
    return a.x*b.x + a.y*b.y + a.z*b.z + a.w*b.w;
}

// async global->LDS DMA, 16B per lane. LDS dest is wave-uniform base
// (HW writes base + lane*16); global src is per-lane.
__device__ __forceinline__ void async_copy16(const float* g, float* l) {
    __builtin_amdgcn_global_load_lds(
        (const __attribute__((address_space(1))) void*)g,
        (__attribute__((address_space(3))) void*)l, 16, 0, 0);
}

// XOR swizzle slot for [128][32] weight tiles (conflict-free b128 reads)
__device__ __forceinline__ int wswz(int e, int q) {
    return (q ^ (e & 7) ^ ((e >> 3) & 3)) * 4;
}

// ---------------- Kernel WT: theta GEMM (0..511) + weight combine (512..576) ----------------
__global__ __launch_bounds__(256) void kWT(const float* __restrict__ x,
                                           const float* __restrict__ Wt,
                                           const float* __restrict__ bt,
                                           const float* __restrict__ Ww,
                                           const float* __restrict__ Wg,
                                           const float* __restrict__ bg,
                                           const float* __restrict__ bw,
                                           float* __restrict__ theta,
                                           float* __restrict__ M,
                                           float* __restrict__ b2) {
    __shared__ float xr[32][132];
    __shared__ float wt[128][32];
    int t = threadIdx.x;
    if (blockIdx.x >= 512) {
        int bid2 = blockIdx.x - 512;
        if (bid2 < 64) {
            int e = bid2 * 2 + (t >> 7);
            int c = t & 127;
            float acc = 0.f;
#pragma unroll 8
            for (int d = 0; d < 128; ++d)
                acc += Ww[e*128 + d] * Wg[d*128 + c];
            M[e*128 + c] = acc;
        } else if (t < 128) {
            float acc = bw[t];
            for (int d = 0; d < 128; ++d)
                acc += Ww[t*128 + d] * bg[d];
            b2[t] = acc;
        }
        return;
    }
    long base = (long)blockIdx.x * (32 * 128);
#pragma unroll
    for (int r = 0; r < 4; ++r) {
        int f = (t + 256*r) * 4;
        int dn = f >> 7, c = f & 127;
        *(float4*)&xr[dn][c] = *(const float4*)(x + base + f);
    }
    float acc[4][4] = {};
    int e0 = t & 31, dn0 = (t >> 5) * 4;
    for (int cb = 0; cb < 4; ++cb) {
        __syncthreads();
#pragma unroll
        for (int r = 0; r < 4; ++r) {
            int f = (t + 256*r) * 4;
            int d = f >> 5, cc = f & 31;
            *(float4*)&wt[d][wswz(d, cc >> 2)] = *(const float4*)(Wt + d*128 + cb*32 + cc);
        }
        __syncthreads();
#pragma unroll
        for (int q = 0; q < 8; ++q) {
            int sw = wswz(e0, q);
            float4 a4[4], m4[4];
#pragma unroll
            for (int j = 0; j < 4; ++j) a4[j] = *(const float4*)&xr[dn0+j][cb*32 + q*4];
#pragma unroll
            for (int i = 0; i < 4; ++i) m4[i] = *(const float4*)&wt[e0 + 32*i][sw];
#pragma unroll
            for (int i = 0; i < 4; ++i)
#pragma unroll
                for (int j = 0; j < 4; ++j)
                    acc[i][j] += dot4(a4[j], m4[i]);
        }
    }
    __syncthreads();
#pragma unroll
    for (int i = 0; i < 4; ++i) {
        float b = bt[e0 + 32*i];
#pragma unroll
        for (int j = 0; j < 4; ++j)
            xr[dn0 + j][e0 + 32*i] = acc[i][j] + b;
    }
    __syncthreads();
#pragma unroll
    for (int r = 0; r < 4; ++r) {
        int f = (t + 256*r) * 4;
        int dn = f >> 7, c = f & 127;
        *(float4*)(theta + base + f) = *(const float4*)&xr[dn][c];
    }
}

// ---------------- Kernel BC: coef (fused kA) + feature stream + GEMM epilogue ----------------
// Block = 16 n-rows x ALL 128 channels; grid 1024 (XCD-swizzled: each XCD's
// bids cover one contiguous half-batch -> gathers hit a 2 MB theta slice in
// its own L2).
// Phase A (fused kA): stage 16 theta rows; gather theta[idx]; logits;
//   softmax -> coefL[16][36] in LDS. Gather overlaps other blocks' streams.
// Phase B: 32 chunks of 4 channels; wave w stages channel ch*4+w's 16x32
//   chunk (2 KB = two 1KB DMAs) into a wave-private 2-slot ring; counted
//   per-wave vmcnt(2) (never 0 till last); NO barriers in the loop. Linear
//   LDS reads (exact DMA layout -> conflict-free); 8-lane shfl reduce.
// Phase C (kC absorbed): y[16][128] = aggL @ M^T + b2 (swizzled mc), yT
//   transpose for coalesced stores, per-block BN partials.
union GU {
    struct { float tc[16][132]; float logits[16][33]; } g;  // 10.5 KB
    float ring[4][2][512];                                   // 16 KB
    float mc[128][32];                                       // 16 KB
    float yT[128][20];                                       // 10 KB
};

__global__ __launch_bounds__(256) void kBC(const int* __restrict__ gi,
                                           const float* __restrict__ theta,
                                           const float* __restrict__ feat,
                                           const float* __restrict__ Mmat,
                                           const float* __restrict__ b2v,
                                           float* __restrict__ y,
                                           float* __restrict__ partial) {
    __shared__ GU u;
    __shared__ float coefL[16][36];
    __shared__ float aggL[16][132];
    int t = threadIdx.x;
    int bid = (blockIdx.x & 7) * 128 + (blockIdx.x >> 3);   // XCD-bijective (1024 = 8*128)
    int b = bid >> 8;
    int n0 = (bid & 255) * 16;
    long trow0 = (long)bid * 16;         // = b*N + n0
    int w = t >> 6, lane = t & 63;
    int r8 = lane >> 3, ks = lane & 7;

    // ---- Phase A: coef for this block's 16 rows (kA fused) ----
    {
        int k = t >> 3, l8 = t & 7;
#pragma unroll
        for (int r = 0; r < 2; ++r) {
            int f = (t + 256*r) * 4;
            int dn = f >> 7, c = f & 127;
            *(float4*)&u.g.tc[dn][c] = *(const float4*)(theta + trow0*128 + f);
        }
        int idxs[16];
#pragma unroll
        for (int dn = 0; dn < 16; ++dn)
            idxs[dn] = gi[(trow0 + dn) * KK + k];
        __syncthreads();
        const float* tbat = theta + (long)b * NN * CC;
#pragma unroll 2
        for (int dn = 0; dn < 16; ++dn) {
            const float* row = tbat + (long)idxs[dn] * CC;
            float p = 0.f;
#pragma unroll
            for (int j = 0; j < 4; ++j) {
                int c = j*32 + l8*4;
                float4 g = *(const float4*)(row + c);
                float4 tcv = *(const float4*)&u.g.tc[dn][c];
                p += dot4(g, tcv);
            }
            p += __shfl_xor(p, 1);
            p += __shfl_xor(p, 2);
            p += __shfl_xor(p, 4);
            if (l8 == 0) u.g.logits[dn][k] = p;
        }
        __syncthreads();
        if (t < 128) {
            int row = t >> 3;
            float l[4];
#pragma unroll
            for (int j = 0; j < 4; ++j) l[j] = u.g.logits[row][l8 + 8*j];
            float m = fmaxf(fmaxf(l[0], l[1]), fmaxf(l[2], l[3]));
            m = fmaxf(m, __shfl_xor(m, 1));
            m = fmaxf(m, __shfl_xor(m, 2));
            m = fmaxf(m, __shfl_xor(m, 4));
            float e[4]; float s = 0.f;
#pragma unroll
            for (int j = 0; j < 4; ++j) { e[j] = __expf(l[j] - m); s += e[j]; }
            s += __shfl_xor(s, 1);
            s += __shfl_xor(s, 2);
            s += __shfl_xor(s, 4);
            float inv = 1.0f / s;
#pragma unroll
            for (int j = 0; j < 4; ++j) coefL[row][l8 + 8*j] = e[j] * inv;
        }
        __syncthreads();   // coefL ready; u.g dead -> ring live
    }

    // coef: rows r8 and 8+r8 at k-slot ks (constant over chunks)
    float4 cf0 = *(const float4*)&coefL[r8][ks * 4];
    float4 cf1 = *(const float4*)&coefL[8 + r8][ks * 4];

    const size_t S = (size_t)NN * KK;
    const float* fbase = feat + (size_t)b * CC * S + (size_t)n0 * KK + lane * 4;
    float* myRing = &u.ring[w][0][0];

    // prologue: chunks 0,1 (channels w, 4+w) into slots 0,1
#pragma unroll
    for (int ch = 0; ch < 2; ++ch) {
        const float* fc = fbase + (size_t)(ch * 4 + w) * S;
        float* ld = myRing + ch * 512;
        async_copy16(fc, ld);
        async_copy16(fc + 256, ld + 256);
    }

#pragma unroll
    for (int ch = 0; ch < 32; ++ch) {
        // this wave's chunk-ch 2 DMAs done; next chunk (2) stays in flight
        if (ch < 31) asm volatile("s_waitcnt vmcnt(2)" ::: "memory");
        else         asm volatile("s_waitcnt vmcnt(0)" ::: "memory");
        const float* sl = myRing + (ch & 1) * 512 + lane * 4;
        float4 f0 = *(const float4*)(sl);          // rows 0..7 sub-block
        float4 f1 = *(const float4*)(sl + 256);    // rows 8..15 sub-block
        float v0 = dot4(f0, cf0);
        float v1 = dot4(f1, cf1);
        v0 += __shfl_xor(v0, 1); v0 += __shfl_xor(v0, 2); v0 += __shfl_xor(v0, 4);
        v1 += __shfl_xor(v1, 1); v1 += __shfl_xor(v1, 2); v1 += __shfl_xor(v1, 4);
        if (ks == 0) {
            aggL[r8][ch * 4 + w]     = v0;
            aggL[8 + r8][ch * 4 + w] = v1;
        }
        // restage (reads above already retired in program order)
        if (ch + 2 < 32) {
            const float* fc = fbase + (size_t)((ch + 2) * 4 + w) * S;
            float* ld = myRing + (ch & 1) * 512;
            async_copy16(fc, ld);
            async_copy16(fc + 256, ld + 256);
        }
    }
    __syncthreads();   // all waves' aggL columns visible; ring dead

    // ---- Phase C: y[16][128] = aggL @ M^T + b2 ----
    float acc[4][2] = {};
    int e0 = t & 31, dn0 = (t >> 5) * 2;
    for (int cb = 0; cb < 4; ++cb) {
        __syncthreads();
#pragma unroll
        for (int r = 0; r < 4; ++r) {
            int f = (t + 256*r) * 4;
            int e = f >> 5, cc = f & 31;
            *(float4*)&u.mc[e][wswz(e, cc >> 2)] = *(const float4*)(Mmat + e*128 + cb*32 + cc);
        }
        __syncthreads();
#pragma unroll
        for (int q = 0; q < 8; ++q) {
            int sw = wswz(e0, q);
            float4 a4[2], m4[4];
#pragma unroll
            for (int j = 0; j < 2; ++j) a4[j] = *(const float4*)&aggL[dn0+j][cb*32 + q*4];
#pragma unroll
            for (int i = 0; i < 4; ++i) m4[i] = *(const float4*)&u.mc[e0 + 32*i][sw];
#pragma unroll
            for (int i = 0; i < 4; ++i)
#pragma unroll
                for (int j = 0; j < 2; ++j)
                    acc[i][j] += dot4(a4[j], m4[i]);
        }
    }
    __syncthreads();   // mc dead; yT aliases
#pragma unroll
    for (int i = 0; i < 4; ++i) {
        int e = e0 + 32*i;
        float bb = b2v[e];
#pragma unroll
        for (int j = 0; j < 2; ++j)
            u.yT[e][dn0 + j] = acc[i][j] + bb;
    }
    __syncthreads();
    // coalesced y stores: thread t -> (e = t>>1, half = t&1), 32 B each
    {
        int e = t >> 1, half = t & 1;
        float4 v0 = *(const float4*)&u.yT[e][half * 8];
        float4 v1 = *(const float4*)&u.yT[e][half * 8 + 4];
        float* dst = y + ((size_t)(b*CC + e)) * NN + n0 + half * 8;
        *(float4*)dst       = v0;
        *(float4*)(dst + 4) = v1;
    }
    // BN partials: per-channel sum/sumsq over this block's 16 rows
    if (t < 128) {
        float s = 0.f, q = 0.f;
#pragma unroll
        for (int j = 0; j < 16; ++j) {
            float v = u.yT[t][j];
            s += v; q += v * v;
        }
        partial[(size_t)bid * 256 + t]       = s;
        partial[(size_t)bid * 256 + 128 + t] = q;
    }
}

// ---------------- Kernel R1: 1024 partial rows -> 64 ----------------
__global__ __launch_bounds__(256) void kR1(const float* __restrict__ partial,
                                           float* __restrict__ partial2) {
    int t = threadIdx.x;
    long b0 = (long)blockIdx.x * 16;
    float acc = 0.f;
#pragma unroll
    for (int j = 0; j < 16; ++j)
        acc += partial[(b0 + j) * 256 + t];
    partial2[(long)blockIdx.x * 256 + t] = acc;
}

// ---------------- Kernel Zf: fused stats (64-row reduce, L2-hot) + normalize ----------------
__global__ __launch_bounds__(256) void kZf(float* __restrict__ y,
                                           const float* __restrict__ partial2,
                                           const float* __restrict__ gamma,
                                           const float* __restrict__ beta) {
    __shared__ float buf[256];
    __shared__ float scs[128];
    __shared__ float shs[128];
    int t = threadIdx.x;
    float acc = 0.f;
#pragma unroll 8
    for (int j = 0; j < 64; ++j)
        acc += partial2[j * 256 + t];
    buf[t] = acc;
    __syncthreads();
    if (t < 128) {
        float S = buf[t], Q = buf[t + 128];
        const float invN = 1.0f / (BB * NN);
        float mean = S * invN;
        float var  = Q * invN - mean * mean;
        float sc = rsqrtf(var + 1e-5f) * gamma[t];
        scs[t] = sc;
        shs[t] = beta[t] - mean * sc;
    }
    __syncthreads();
    int idx = blockIdx.x * 256 + t;   // float4 index
#pragma unroll
    for (int r = 0; r < 2; ++r) {
        int i = idx + r * 262144;
        int e = (i >> 10) & 127;
        float sc = scs[e], sh = shs[e];
        float4 v = ((float4*)y)[i];
        v.x = v.x * sc + sh;
        v.y = v.y * sc + sh;
        v.z = v.z * sc + sh;
        v.w = v.w * sc + sh;
        ((float4*)y)[i] = v;
    }
}

extern "C" void kernel_launch(void* const* d_in, const int* in_sizes, int n_in,
                              void* d_out, int out_size, void* d_ws, size_t ws_size,
                              hipStream_t stream) {
    const int*   gi    = (const int*)d_in[0];
    const float* x     = (const float*)d_in[1];
    const float* feat  = (const float*)d_in[2];
    const float* Wt    = (const float*)d_in[3];
    const float* bt    = (const float*)d_in[4];
    const float* Wg    = (const float*)d_in[5];
    const float* bg    = (const float*)d_in[6];
    const float* Ww    = (const float*)d_in[7];
    const float* bw    = (const float*)d_in[8];
    const float* gamma = (const float*)d_in[9];
    const float* beta  = (const float*)d_in[10];

    float* y  = (float*)d_out;
    float* ws = (float*)d_ws;
    float* theta    = ws + THETA_OFF;
    float* Mmat     = ws + M_OFF;
    float* b2       = ws + B2_OFF;
    float* partial  = ws + PART_OFF;
    float* partial2 = ws + PART2_OFF;

    kWT<<<577, 256, 0, stream>>>(x, Wt, bt, Ww, Wg, bg, bw, theta, Mmat, b2);
    kBC<<<1024, 256, 0, stream>>>(gi, theta, feat, Mmat, b2, y, partial);
    kR1<<<64, 256, 0, stream>>>(partial, partial2);
    kZf<<<1024, 256, 0, stream>>>(y, partial2, gamma, beta);
}

// Round 18
// 94.559 us; speedup vs baseline: 1.1906x; 1.1906x over previous
//
#include <hip/hip_runtime.h>
#include <hip/hip_bf16.h>

// Problem constants
#define BB 4
#define CC 128
#define NN 4096
#define KK 32
// ws layout (floats)
#define THETA_OFF  0
#define THETA_SZ   (BB*NN*CC)            // 2097152 floats (8 MB)
#define M_OFF      (THETA_OFF + THETA_SZ)
#define M_SZ       (CC*CC)
#define B2_OFF     (M_OFF + M_SZ)
#define COEF_OFF   (B2_OFF + 128)
#define COEF_SZ    (BB*NN*KK)
#define PART_OFF   (COEF_OFF + COEF_SZ)
#define PART_SZ    (1024*256)
#define PART2_OFF  (PART_OFF + PART_SZ)
#define PART2_SZ   (64*256)

__device__ __forceinline__ float dot4(float4 a, float4 b) {
    return a.x*b.x + a.y*b.y + a.z*b.z + a.w*b.w;
}

// async global->LDS DMA, 16B per lane. LDS dest is wave-uniform base
// (HW writes base + lane*16); global src is per-lane.
__device__ __forceinline__ void async_copy16(const float* g, float* l) {
    __builtin_amdgcn_global_load_lds(
        (const __attribute__((address_space(1))) void*)g,
        (__attribute__((address_space(3))) void*)l, 16, 0, 0);
}

// XOR swizzle slot for [128][32] weight tiles (conflict-free b128 reads)
__device__ __forceinline__ int wswz(int e, int q) {
    return (q ^ (e & 7) ^ ((e >> 3) & 3)) * 4;
}

// ---------------- Kernel WT: theta GEMM (512 blocks) ----------------
__global__ __launch_bounds__(256) void kWT(const float* __restrict__ x,
                                           const float* __restrict__ Wt,
                                           const float* __restrict__ bt,
                                           float* __restrict__ theta) {
    __shared__ float xr[32][132];
    __shared__ float wt[128][32];
    int t = threadIdx.x;
    long base = (long)blockIdx.x * (32 * 128);
#pragma unroll
    for (int r = 0; r < 4; ++r) {
        int f = (t + 256*r) * 4;
        int dn = f >> 7, c = f & 127;
        *(float4*)&xr[dn][c] = *(const float4*)(x + base + f);
    }
    float acc[4][4] = {};
    int e0 = t & 31, dn0 = (t >> 5) * 4;
    for (int cb = 0; cb < 4; ++cb) {
        __syncthreads();
#pragma unroll
        for (int r = 0; r < 4; ++r) {
            int f = (t + 256*r) * 4;
            int d = f >> 5, cc = f & 31;
            *(float4*)&wt[d][wswz(d, cc >> 2)] = *(const float4*)(Wt + d*128 + cb*32 + cc);
        }
        __syncthreads();
#pragma unroll
        for (int q = 0; q < 8; ++q) {
            int sw = wswz(e0, q);
            float4 a4[4], m4[4];
#pragma unroll
            for (int j = 0; j < 4; ++j) a4[j] = *(const float4*)&xr[dn0+j][cb*32 + q*4];
#pragma unroll
            for (int i = 0; i < 4; ++i) m4[i] = *(const float4*)&wt[e0 + 32*i][sw];
#pragma unroll
            for (int i = 0; i < 4; ++i)
#pragma unroll
                for (int j = 0; j < 4; ++j)
                    acc[i][j] += dot4(a4[j], m4[i]);
        }
    }
    __syncthreads();
#pragma unroll
    for (int i = 0; i < 4; ++i) {
        float b = bt[e0 + 32*i];
#pragma unroll
        for (int j = 0; j < 4; ++j)
            xr[dn0 + j][e0 + 32*i] = acc[i][j] + b;
    }
    __syncthreads();
#pragma unroll
    for (int r = 0; r < 4; ++r) {
        int f = (t + 256*r) * 4;
        int dn = f >> 7, c = f & 127;
        *(float4*)(theta + base + f) = *(const float4*)&xr[dn][c];
    }
}

// ---------------- Kernel A: coef softmax (2048) + weight combine (65) ----------------
__global__ __launch_bounds__(256) void kA(const int* __restrict__ gi,
                                          const float* __restrict__ theta,
                                          const float* __restrict__ Ww,
                                          const float* __restrict__ Wg,
                                          const float* __restrict__ bg,
                                          const float* __restrict__ bw,
                                          float* __restrict__ M,
                                          float* __restrict__ b2,
                                          float* __restrict__ coefG) {
    int t = threadIdx.x;
    if (blockIdx.x >= 2048) {
        int bid2 = blockIdx.x - 2048;
        if (bid2 < 64) {
            int e = bid2 * 2 + (t >> 7);
            int c = t & 127;
            float acc = 0.f;
#pragma unroll 8
            for (int d = 0; d < 128; ++d)
                acc += Ww[e*128 + d] * Wg[d*128 + c];
            M[e*128 + c] = acc;
        } else if (t < 128) {
            float acc = bw[t];
            for (int d = 0; d < 128; ++d)
                acc += Ww[t*128 + d] * bg[d];
            b2[t] = acc;
        }
        return;
    }
    __shared__ float tc[8][132];
    __shared__ float logits[8][33];
    int bid = (blockIdx.x & 7) * 256 + (blockIdx.x >> 3);
    long trow0 = (long)bid * 8;
    int b = bid >> 9;
    int k = t >> 3, l8 = t & 7;
    {
        int f = t * 4;
        int dn = f >> 7, c = f & 127;
        *(float4*)&tc[dn][c] = *(const float4*)(theta + trow0*128 + f);
    }
    int idxs[8];
#pragma unroll
    for (int dn = 0; dn < 8; ++dn)
        idxs[dn] = gi[(trow0 + dn) * KK + k];
    __syncthreads();
    const float* tbat = theta + (long)b * NN * CC;
#pragma unroll 2
    for (int dn = 0; dn < 8; ++dn) {
        const float* row = tbat + (long)idxs[dn] * CC;
        float p = 0.f;
#pragma unroll
        for (int j = 0; j < 4; ++j) {
            int c = j*32 + l8*4;
            float4 g = *(const float4*)(row + c);
            float4 tcv = *(const float4*)&tc[dn][c];
            p += dot4(g, tcv);
        }
        p += __shfl_xor(p, 1);
        p += __shfl_xor(p, 2);
        p += __shfl_xor(p, 4);
        if (l8 == 0) logits[dn][k] = p;
    }
    __syncthreads();
    if (t < 64) {
        int row = t >> 3;
        float l[4];
#pragma unroll
        for (int j = 0; j < 4; ++j) l[j] = logits[row][l8 + 8*j];
        float m = fmaxf(fmaxf(l[0], l[1]), fmaxf(l[2], l[3]));
        m = fmaxf(m, __shfl_xor(m, 1));
        m = fmaxf(m, __shfl_xor(m, 2));
        m = fmaxf(m, __shfl_xor(m, 4));
        float e[4]; float s = 0.f;
#pragma unroll
        for (int j = 0; j < 4; ++j) { e[j] = __expf(l[j] - m); s += e[j]; }
        s += __shfl_xor(s, 1);
        s += __shfl_xor(s, 2);
        s += __shfl_xor(s, 4);
        float inv = 1.0f / s;
#pragma unroll
        for (int j = 0; j < 4; ++j)
            coefG[(trow0 + row) * KK + l8 + 8*j] = e[j] * inv;
    }
}

// ---------------- Kernel BC: feature stream + in-block GEMM epilogue ----------------
// Block = 16 n-rows x ALL 128 channels; grid 1024 (XCD-swizzled).
// Stream: 32 chunks of 4 channels; wave w stages channel ch*4+w's 16x32
// chunk (2 KB = two 1KB DMAs) into a wave-private 2-slot ring; counted
// per-wave vmcnt(2) (never 0 till last chunk); NO barriers in the loop.
// Lane l: r8 = l>>3 covers rows {r8, 8+r8}, k-slot (l&7)*4; linear LDS
// reads (exact DMA layout -> conflict-free); 8-lane shfl reduce.
// Epilogue (kC absorbed): y[16][128] = aggL @ M^T + b2 with swizzled mc,
// yT transpose for coalesced stores, per-block BN partials.
__global__ __launch_bounds__(256) void kBC(const float* __restrict__ coefG,
                                           const float* __restrict__ feat,
                                           const float* __restrict__ Mmat,
                                           const float* __restrict__ b2v,
                                           float* __restrict__ y,
                                           float* __restrict__ partial) {
    __shared__ float ring[4][2][512];    // [wave][slot][16r x 32k] 16 KB; reused by epilogue
    __shared__ float aggL[16][132];      // 8.4 KB
    int t = threadIdx.x;
    int bid = (blockIdx.x & 7) * 128 + (blockIdx.x >> 3);   // XCD-bijective (1024 = 8*128)
    int b = bid >> 8;
    int n0 = (bid & 255) * 16;
    long trow0 = (long)bid * 16;         // = b*N + n0
    int w = t >> 6, lane = t & 63;
    int r8 = lane >> 3, ks = lane & 7;

    // coef: rows r8 and 8+r8 at k-slot ks (constant over chunks)
    float4 cf0 = *(const float4*)(coefG + (trow0 + r8) * KK + ks * 4);
    float4 cf1 = *(const float4*)(coefG + (trow0 + 8 + r8) * KK + ks * 4);
    asm volatile("" :: "v"(cf0.x), "v"(cf0.y), "v"(cf0.z), "v"(cf0.w));
    asm volatile("" :: "v"(cf1.x), "v"(cf1.y), "v"(cf1.z), "v"(cf1.w));

    const size_t S = (size_t)NN * KK;
    const float* fbase = feat + (size_t)b * CC * S + (size_t)n0 * KK + lane * 4;
    float* myRing = &ring[w][0][0];

    // prologue: chunks 0,1 (channels w, 4+w) into slots 0,1
#pragma unroll
    for (int ch = 0; ch < 2; ++ch) {
        const float* fc = fbase + (size_t)(ch * 4 + w) * S;
        float* ld = myRing + ch * 512;
        async_copy16(fc, ld);
        async_copy16(fc + 256, ld + 256);
    }

#pragma unroll
    for (int ch = 0; ch < 32; ++ch) {
        // this wave's chunk-ch 2 DMAs done; next chunk (2) stays in flight
        if (ch < 31) asm volatile("s_waitcnt vmcnt(2)" ::: "memory");
        else         asm volatile("s_waitcnt vmcnt(0)" ::: "memory");
        const float* sl = myRing + (ch & 1) * 512 + lane * 4;
        float4 f0 = *(const float4*)(sl);          // rows 0..7 sub-block
        float4 f1 = *(const float4*)(sl + 256);    // rows 8..15 sub-block
        float v0 = dot4(f0, cf0);
        float v1 = dot4(f1, cf1);
        v0 += __shfl_xor(v0, 1); v0 += __shfl_xor(v0, 2); v0 += __shfl_xor(v0, 4);
        v1 += __shfl_xor(v1, 1); v1 += __shfl_xor(v1, 2); v1 += __shfl_xor(v1, 4);
        if (ks == 0) {
            aggL[r8][ch * 4 + w]     = v0;
            aggL[8 + r8][ch * 4 + w] = v1;
        }
        // restage (reads above already retired in program order)
        if (ch + 2 < 32) {
            const float* fc = fbase + (size_t)((ch + 2) * 4 + w) * S;
            float* ld = myRing + (ch & 1) * 512;
            async_copy16(fc, ld);
            async_copy16(fc + 256, ld + 256);
        }
    }
    __syncthreads();   // all waves' aggL columns visible; ring dead

    // ---- epilogue: y[16][128] = aggL @ M^T + b2 ----
    float (*mc)[32] = (float(*)[32])&ring[0][0][0];   // [128][32] 16 KB (= ring)
    float acc[4][2] = {};
    int e0 = t & 31, dn0 = (t >> 5) * 2;
    for (int cb = 0; cb < 4; ++cb) {
        __syncthreads();
#pragma unroll
        for (int r = 0; r < 4; ++r) {
            int f = (t + 256*r) * 4;
            int e = f >> 5, cc = f & 31;
            *(float4*)&mc[e][wswz(e, cc >> 2)] = *(const float4*)(Mmat + e*128 + cb*32 + cc);
        }
        __syncthreads();
#pragma unroll
        for (int q = 0; q < 8; ++q) {
            int sw = wswz(e0, q);
            float4 a4[2], m4[4];
#pragma unroll
            for (int j = 0; j < 2; ++j) a4[j] = *(const float4*)&aggL[dn0+j][cb*32 + q*4];
#pragma unroll
            for (int i = 0; i < 4; ++i) m4[i] = *(const float4*)&mc[e0 + 32*i][sw];
#pragma unroll
            for (int i = 0; i < 4; ++i)
#pragma unroll
                for (int j = 0; j < 2; ++j)
                    acc[i][j] += dot4(a4[j], m4[i]);
        }
    }
    __syncthreads();   // mc dead; yT aliases ring
    float (*yT)[20] = (float(*)[20])&ring[0][0][0];   // [128][20] 10 KB, padded
#pragma unroll
    for (int i = 0; i < 4; ++i) {
        int e = e0 + 32*i;
        float bb = b2v[e];
#pragma unroll
        for (int j = 0; j < 2; ++j)
            yT[e][dn0 + j] = acc[i][j] + bb;
    }
    __syncthreads();
    // coalesced y stores: thread t -> (e = t>>1, half = t&1), 32 B each
    {
        int e = t >> 1, half = t & 1;
        float4 v0 = *(const float4*)&yT[e][half * 8];
        float4 v1 = *(const float4*)&yT[e][half * 8 + 4];
        float* dst = y + ((size_t)(b*CC + e)) * NN + n0 + half * 8;
        *(float4*)dst       = v0;
        *(float4*)(dst + 4) = v1;
    }
    // BN partials: per-channel sum/sumsq over this block's 16 rows
    if (t < 128) {
        float s = 0.f, q = 0.f;
#pragma unroll
        for (int j = 0; j < 16; ++j) {
            float v = yT[t][j];
            s += v; q += v * v;
        }
        partial[(size_t)bid * 256 + t]       = s;
        partial[(size_t)bid * 256 + 128 + t] = q;
    }
}

// ---------------- Kernel R1: 1024 partial rows -> 64 ----------------
__global__ __launch_bounds__(256) void kR1(const float* __restrict__ partial,
                                           float* __restrict__ partial2) {
    int t = threadIdx.x;
    long b0 = (long)blockIdx.x * 16;
    float acc = 0.f;
#pragma unroll
    for (int j = 0; j < 16; ++j)
        acc += partial[(b0 + j) * 256 + t];
    partial2[(long)blockIdx.x * 256 + t] = acc;
}

// ---------------- Kernel Zf: fused stats (64-row reduce, L2-hot) + normalize ----------------
__global__ __launch_bounds__(256) void kZf(float* __restrict__ y,
                                           const float* __restrict__ partial2,
                                           const float* __restrict__ gamma,
                                           const float* __restrict__ beta) {
    __shared__ float buf[256];
    __shared__ float scs[128];
    __shared__ float shs[128];
    int t = threadIdx.x;
    float acc = 0.f;
#pragma unroll 8
    for (int j = 0; j < 64; ++j)
        acc += partial2[j * 256 + t];
    buf[t] = acc;
    __syncthreads();
    if (t < 128) {
        float S = buf[t], Q = buf[t + 128];
        const float invN = 1.0f / (BB * NN);
        float mean = S * invN;
        float var  = Q * invN - mean * mean;
        float sc = rsqrtf(var + 1e-5f) * gamma[t];
        scs[t] = sc;
        shs[t] = beta[t] - mean * sc;
    }
    __syncthreads();
    int idx = blockIdx.x * 256 + t;   // float4 index
#pragma unroll
    for (int r = 0; r < 2; ++r) {
        int i = idx + r * 262144;
        int e = (i >> 10) & 127;
        float sc = scs[e], sh = shs[e];
        float4 v = ((float4*)y)[i];
        v.x = v.x * sc + sh;
        v.y = v.y * sc + sh;
        v.z = v.z * sc + sh;
        v.w = v.w * sc + sh;
        ((float4*)y)[i] = v;
    }
}

extern "C" void kernel_launch(void* const* d_in, const int* in_sizes, int n_in,
                              void* d_out, int out_size, void* d_ws, size_t ws_size,
                              hipStream_t stream) {
    const int*   gi    = (const int*)d_in[0];
    const float* x     = (const float*)d_in[1];
    const float* feat  = (const float*)d_in[2];
    const float* Wt    = (const float*)d_in[3];
    const float* bt    = (const float*)d_in[4];
    const float* Wg    = (const float*)d_in[5];
    const float* bg    = (const float*)d_in[6];
    const float* Ww    = (const float*)d_in[7];
    const float* bw    = (const float*)d_in[8];
    const float* gamma = (const float*)d_in[9];
    const float* beta  = (const float*)d_in[10];

    float* y  = (float*)d_out;
    float* ws = (float*)d_ws;
    float* theta    = ws + THETA_OFF;
    float* Mmat     = ws + M_OFF;
    float* b2       = ws + B2_OFF;
    float* coefG    = ws + COEF_OFF;
    float* partial  = ws + PART_OFF;
    float* partial2 = ws + PART2_OFF;

    kWT<<<512, 256, 0, stream>>>(x, Wt, bt, theta);
    kA<<<2113, 256, 0, stream>>>(gi, theta, Ww, Wg, bg, bw, Mmat, b2, coefG);
    kBC<<<1024, 256, 0, stream>>>(coefG, feat, Mmat, b2, y, partial);
    kR1<<<64, 256, 0, stream>>>(partial, partial2);
    kZf<<<1024, 256, 0, stream>>>(y, partial2, gamma, beta);
}